// Round 17
// baseline (46.822 us; speedup 1.0000x reference)
//
#include <hip/hip_runtime.h>
#include <hip/hip_bf16.h>

#define NN 4096
#define DD 768
#define CCL 97
#define KI 24                // 24 k-chunks of K=32 per 32-row group
#define NT 12                // 12 K-tiles of 64
#define FSCALE 16.0f

typedef __attribute__((ext_vector_type(2))) long i64x2;
typedef __attribute__((ext_vector_type(16))) float f32x16;
typedef unsigned long long u64;

// workspace layout (bytes)
#define SZ_FT    (NN*DD)                    // 3.1 MB fp8 fragment-tiled F
#define OFF_R    (SZ_FT)
#define OFF_S    (OFF_R + NN*4)
#define OFF_C    (OFF_S + NN*4)
#define OFF_BITS (OFF_C + NN*4)             // 4096 * 16B
#define OFF_LM   (OFF_BITS + NN*16)         // 4096 f32

__device__ __forceinline__ ulonglong2 shfl_bits(ulonglong2 v, int src) {
  ulonglong2 r;
  r.x = __shfl((u64)v.x, src, 64);
  r.y = __shfl((u64)v.y, src, 64);
  return r;
}
__device__ __forceinline__ bool ovl(ulonglong2 a, ulonglong2 b) {
  return ((a.x & b.x) | (a.y & b.y)) != 0ULL;
}

__global__ void prep_bits_kernel(const int* __restrict__ labels,
                                 ulonglong2* __restrict__ bits,
                                 float* __restrict__ lm,
                                 float* __restrict__ R, float* __restrict__ S,
                                 float* __restrict__ Cc) {
  int gw = (blockIdx.x * blockDim.x + threadIdx.x) >> 6;
  int lane = threadIdx.x & 63;
  if (gw >= NN) return;
  const int* lr = labels + (long)gw * CCL;
  int v0 = lr[lane];
  int c1 = 64 + lane;
  int v1 = (c1 < CCL) ? lr[c1] : 0;
  u64 m0 = __ballot(v0 == 1);
  u64 m1 = __ballot(v1 == 1);
  if (lane == 0) {
    bits[gw] = make_ulonglong2(m0, m1);
    lm[gw] = (lr[0] != 1) ? 1.0f : 0.0f;
    R[gw] = 0.f; S[gw] = 0.f; Cc[gw] = 0.f;
  }
}

// f32 [N][D] -> fp8 e4m3 (x FSCALE); chunk(g32, ks) = 1KB at (g32*KI+ks)*1024;
// lane (l31,h) slot = l31*32 + h*16; bytes [0,8)=k0..7|[8,16)=k16..23|[16,24)=k8..15|[24,32)=k24..31
__global__ void convert_kernel(const float* __restrict__ F, char* __restrict__ Ft) {
  int idx = blockIdx.x * 256 + threadIdx.x;
  int r = idx / 96, kc = idx - r * 96;
  const float* src = F + (long)r * DD + kc * 8;
  float f[8];
#pragma unroll
  for (int j = 0; j < 8; ++j) f[j] = src[j] * FSCALE;
  int lo = __builtin_amdgcn_cvt_pk_fp8_f32(f[0], f[1], 0, false);
  lo = __builtin_amdgcn_cvt_pk_fp8_f32(f[2], f[3], lo, true);
  int hi = __builtin_amdgcn_cvt_pk_fp8_f32(f[4], f[5], 0, false);
  hi = __builtin_amdgcn_cvt_pk_fp8_f32(f[6], f[7], hi, true);
  int g32 = r >> 5, l31 = r & 31;
  int ks32 = kc >> 2, k8 = kc & 3;
  int hp = k8 & 1, m = k8 >> 1;
  long off = (long)(g32 * KI + ks32) * 1024 + l31 * 32 + hp * 16 + m * 8;
  *((int2*)(Ft + off)) = make_int2(lo, hi);
}

__device__ __forceinline__ void gload_lds16(const char* gsrc, char* ldst) {
  __builtin_amdgcn_global_load_lds(
      (const __attribute__((address_space(1))) void*)gsrc,
      (__attribute__((address_space(3))) void*)ldst, 16, 0, 0);
}

#define WAITV(N) asm volatile("s_waitcnt vmcnt(" #N ")" ::: "memory")
#define LGKM0()  asm volatile("s_waitcnt lgkmcnt(0)" ::: "memory")
#define BAR()    __builtin_amdgcn_s_barrier()

// 256x256 block tile, 8 waves (2M x 4N, each 128x64), BK=64, ring-3 LDS (96KB),
// 4 phases per K-tile: {ds_read || stage(t+2) -> bar -> lgkm0 -> prio1 -> 8 MFMA
// -> prio0 -> bar}; boundary vmcnt(4) counted (never 0 mid-loop). 256 blocks = 1/CU.
__global__ __launch_bounds__(512, 2) void main_kernel(
    const char* __restrict__ Ft, const ulonglong2* __restrict__ bits,
    float* __restrict__ R, float* __restrict__ S, float* __restrict__ Cc) {
  __shared__ char lds[3][32768];         // [buf][A 16KB | B 16KB]
  const int tid = threadIdx.x;
  const int wave = tid >> 6, lane = tid & 63;
  const int wm = wave >> 2, wn = wave & 3;
  const int l31 = lane & 31, h = lane >> 5;

  // XCD swizzle (256 = 8*32, bijective); supertile (I,J) of 256x256
  int b0 = blockIdx.x;
  int nb = (b0 & 7) * 32 + (b0 >> 3);
  const int I = nb >> 4, J = nb & 15;

  // stage unit u (0..3): chunk id = u*8+wave; 0-15 A (colgroup g=cid>>1, kc=cid&1),
  // 16-31 B (rowgroup). One gload_lds (1KB) per wave per unit.
#define STAGE(t_, u_) do {                                                     \
    int cid = (u_) * 8 + wave;                                                 \
    int isA = (cid < 16) ? 1 : 0;                                              \
    int cg = (isA ? cid : cid - 16) >> 1;                                      \
    int ck = cid & 1;                                                          \
    const char* gs = Ft + ((long)(((isA ? J : I) * 8 + cg) * KI) + (t_) * 2 + ck) * 1024 + lane * 16; \
    char* ds = &lds[(t_) % 3][0] + (isA ? 0 : 16384) + (cg * 2 + ck) * 1024;   \
    gload_lds16(gs, ds);                                                       \
  } while (0)

  f32x16 a00, a01, a02, a03;             // a{cj}{ri}
  f32x16 a10, a11, a12, a13;
  a00 = (f32x16)(0.f); a01 = (f32x16)(0.f); a02 = (f32x16)(0.f); a03 = (f32x16)(0.f);
  a10 = (f32x16)(0.f); a11 = (f32x16)(0.f); a12 = (f32x16)(0.f); a13 = (f32x16)(0.f);

  // per-wave ds_read offsets
  const int offA0 = ((wn * 2 + 0) * 2) * 1024 + lane * 16;   // (cj0, kc) -> +kc*1024
  const int offA1 = ((wn * 2 + 1) * 2) * 1024 + lane * 16;
  const int offB_ = 16384 + (wm * 4) * 2 * 1024 + lane * 16; // (ri, kc) -> +ri*2048+kc*1024

  // prologue: stage tiles 0 and 1 (4 units each)
#pragma unroll
  for (int u = 0; u < 4; ++u) STAGE(0, u);
#pragma unroll
  for (int u = 0; u < 4; ++u) STAGE(1, u);

#define MM(d, va, vb) d = __builtin_amdgcn_mfma_f32_32x32x16_fp8_fp8(va, vb, d, 0, 0, 0)

  for (int t = 0; t < NT; ++t) {
    // tile boundary: drain tile t's 4 stage units (keep t+1, t+2 partial in flight)
    if (t < NT - 1) WAITV(4);
    else            WAITV(0);
    BAR();
    asm volatile("" ::: "memory");
    const char* cb = &lds[t % 3][0];
    const bool st = (t + 2 < NT);

    i64x2 A0, A1, B0, B1, B2, B3;
    // ---- phase 0: kc=0, A + B(ri0,ri1); MFMA quads (cj*,ri0/1) ----
    A0 = *(const i64x2*)(cb + offA0);
    A1 = *(const i64x2*)(cb + offA1);
    B0 = *(const i64x2*)(cb + offB_);
    B1 = *(const i64x2*)(cb + offB_ + 2048);
    if (st) STAGE(t + 2, 0);
    BAR();
    LGKM0();
    __builtin_amdgcn_s_setprio(1);
    MM(a00, A0.x, B0.x); MM(a10, A1.x, B0.x); MM(a01, A0.x, B1.x); MM(a11, A1.x, B1.x);
    MM(a00, A0.y, B0.y); MM(a10, A1.y, B0.y); MM(a01, A0.y, B1.y); MM(a11, A1.y, B1.y);
    __builtin_amdgcn_s_setprio(0);
    BAR();
    // ---- phase 1: B(ri2,ri3) kc=0 ----
    B2 = *(const i64x2*)(cb + offB_ + 2 * 2048);
    B3 = *(const i64x2*)(cb + offB_ + 3 * 2048);
    if (st) STAGE(t + 2, 1);
    BAR();
    LGKM0();
    __builtin_amdgcn_s_setprio(1);
    MM(a02, A0.x, B2.x); MM(a12, A1.x, B2.x); MM(a03, A0.x, B3.x); MM(a13, A1.x, B3.x);
    MM(a02, A0.y, B2.y); MM(a12, A1.y, B2.y); MM(a03, A0.y, B3.y); MM(a13, A1.y, B3.y);
    __builtin_amdgcn_s_setprio(0);
    BAR();
    // ---- phase 2: kc=1, A + B(ri0,ri1) ----
    A0 = *(const i64x2*)(cb + offA0 + 1024);
    A1 = *(const i64x2*)(cb + offA1 + 1024);
    B0 = *(const i64x2*)(cb + offB_ + 1024);
    B1 = *(const i64x2*)(cb + offB_ + 2048 + 1024);
    if (st) STAGE(t + 2, 2);
    BAR();
    LGKM0();
    __builtin_amdgcn_s_setprio(1);
    MM(a00, A0.x, B0.x); MM(a10, A1.x, B0.x); MM(a01, A0.x, B1.x); MM(a11, A1.x, B1.x);
    MM(a00, A0.y, B0.y); MM(a10, A1.y, B0.y); MM(a01, A0.y, B1.y); MM(a11, A1.y, B1.y);
    __builtin_amdgcn_s_setprio(0);
    BAR();
    // ---- phase 3: B(ri2,ri3) kc=1 ----
    B2 = *(const i64x2*)(cb + offB_ + 2 * 2048 + 1024);
    B3 = *(const i64x2*)(cb + offB_ + 3 * 2048 + 1024);
    if (st) STAGE(t + 2, 3);
    BAR();
    LGKM0();
    __builtin_amdgcn_s_setprio(1);
    MM(a02, A0.x, B2.x); MM(a12, A1.x, B2.x); MM(a03, A0.x, B3.x); MM(a13, A1.x, B3.x);
    MM(a02, A0.y, B2.y); MM(a12, A1.y, B2.y); MM(a03, A0.y, B3.y); MM(a13, A1.y, B3.y);
    __builtin_amdgcn_s_setprio(0);
    BAR();
  }
#undef STAGE
#undef MM

  // ---- epilogue: row stats, direct atomics per wave ----
  // row(ri) = (I*8 + wm*4 + ri)*32 + l31 ; col(cj,reg,h) = (J*8 + wn*2 + cj)*32 + crow
  const float sscale = 1.0f / (FSCALE * FSCALE * 2.0f);
  const int gr0 = I * 8 + wm * 4;
  const int gc0 = J * 8 + wn * 2;
  const ulonglong2 rb0 = bits[(gr0 + 0) * 32 + l31];
  const ulonglong2 rb1 = bits[(gr0 + 1) * 32 + l31];
  const ulonglong2 rb2 = bits[(gr0 + 2) * 32 + l31];
  const ulonglong2 rb3 = bits[(gr0 + 3) * 32 + l31];
  const ulonglong2 cb0 = bits[(gc0 + 0) * 32 + l31];
  const ulonglong2 cb1 = bits[(gc0 + 1) * 32 + l31];

  float rs0 = 0.f, ss0 = 0.f, cs0 = 0.f;
  float rs1 = 0.f, ss1 = 0.f, cs1 = 0.f;
  float rs2 = 0.f, ss2 = 0.f, cs2 = 0.f;
  float rs3 = 0.f, ss3 = 0.f, cs3 = 0.f;

#pragma unroll
  for (int reg = 0; reg < 16; ++reg) {
    const int crow = (reg & 3) + 8 * (reg >> 2) + 4 * h;
    const ulonglong2 cq0 = shfl_bits(cb0, crow);
    const ulonglong2 cq1 = shfl_bits(cb1, crow);
#define EPI(acc, rbv, rs, ss, cs, gcv, cqv, grv)  do {                     \
      float v = acc[reg] * sscale;                                          \
      float e = __expf(v);                                                  \
      float o = ovl(rbv, cqv) ? 1.f : 0.f;                                  \
      bool dg = ((grv) == (gcv)) && (crow == l31);                          \
      if (!dg) { rs += e; ss = fmaf(o, v, ss); cs += o; }                   \
    } while (0)
    EPI(a00, rb0, rs0, ss0, cs0, gc0 + 0, cq0, gr0 + 0);
    EPI(a01, rb1, rs1, ss1, cs1, gc0 + 0, cq0, gr0 + 1);
    EPI(a02, rb2, rs2, ss2, cs2, gc0 + 0, cq0, gr0 + 2);
    EPI(a03, rb3, rs3, ss3, cs3, gc0 + 0, cq0, gr0 + 3);
    EPI(a10, rb0, rs0, ss0, cs0, gc0 + 1, cq1, gr0 + 0);
    EPI(a11, rb1, rs1, ss1, cs1, gc0 + 1, cq1, gr0 + 1);
    EPI(a12, rb2, rs2, ss2, cs2, gc0 + 1, cq1, gr0 + 2);
    EPI(a13, rb3, rs3, ss3, cs3, gc0 + 1, cq1, gr0 + 3);
#undef EPI
  }
  // combine h-halves (same rows, disjoint cols)
  rs0 += __shfl_xor(rs0, 32, 64); ss0 += __shfl_xor(ss0, 32, 64); cs0 += __shfl_xor(cs0, 32, 64);
  rs1 += __shfl_xor(rs1, 32, 64); ss1 += __shfl_xor(ss1, 32, 64); cs1 += __shfl_xor(cs1, 32, 64);
  rs2 += __shfl_xor(rs2, 32, 64); ss2 += __shfl_xor(ss2, 32, 64); cs2 += __shfl_xor(cs2, 32, 64);
  rs3 += __shfl_xor(rs3, 32, 64); ss3 += __shfl_xor(ss3, 32, 64); cs3 += __shfl_xor(cs3, 32, 64);
  if (lane < 32) {
    int r0 = (gr0 + 0) * 32 + lane;
    int r1 = (gr0 + 1) * 32 + lane;
    int r2 = (gr0 + 2) * 32 + lane;
    int r3 = (gr0 + 3) * 32 + lane;
    atomicAdd(R + r0, rs0); atomicAdd(S + r0, ss0); atomicAdd(Cc + r0, cs0);
    atomicAdd(R + r1, rs1); atomicAdd(S + r1, ss1); atomicAdd(Cc + r1, cs1);
    atomicAdd(R + r2, rs2); atomicAdd(S + r2, ss2); atomicAdd(Cc + r2, cs2);
    atomicAdd(R + r3, rs3); atomicAdd(S + r3, ss3); atomicAdd(Cc + r3, cs3);
  }
}

__global__ __launch_bounds__(1024) void finalize_kernel(
    const float* __restrict__ R, const float* __restrict__ S,
    const float* __restrict__ Cc, const float* __restrict__ lm,
    float* __restrict__ out) {
  int tid = threadIdx.x;
  float s1 = 0.f, s2 = 0.f, slm = 0.f;
  for (int i = tid; i < NN; i += 1024) {
    float r = R[i], s = S[i], c = Cc[i], l = lm[i];
    float logR = __logf(r);
    float lp1 = (c > 0.f) ? (s - c * logR) / c : 0.f;
    float lp2 = (c == 0.f) ? (0.5f - logR) : 0.f;
    s1 += lp1 * l; s2 += lp2; slm += l;
  }
#pragma unroll
  for (int d = 1; d < 64; d <<= 1) {
    s1 += __shfl_xor(s1, d, 64);
    s2 += __shfl_xor(s2, d, 64);
    slm += __shfl_xor(slm, d, 64);
  }
  __shared__ float w1[16], w2[16], w3[16];
  int w = tid >> 6;
  if ((tid & 63) == 0) { w1[w] = s1; w2[w] = s2; w3[w] = slm; }
  __syncthreads();
  if (tid == 0) {
    float a = 0.f, b = 0.f, c2 = 0.f;
    for (int q = 0; q < 16; ++q) { a += w1[q]; b += w2[q]; c2 += w3[q]; }
    const float inv = 1.0f / (float)NN;
    out[0] = -2.0f * (a * inv + b * c2 * inv * inv);
  }
}

extern "C" void kernel_launch(void* const* d_in, const int* in_sizes, int n_in,
                              void* d_out, int out_size, void* d_ws, size_t ws_size,
                              hipStream_t stream) {
  const float* F = (const float*)d_in[0];
  const int* labels = (const int*)d_in[1];
  float* out = (float*)d_out;
  char* ws = (char*)d_ws;

  char* Ft = ws;
  float* R = (float*)(ws + OFF_R);
  float* S = (float*)(ws + OFF_S);
  float* Cc = (float*)(ws + OFF_C);
  ulonglong2* bits = (ulonglong2*)(ws + OFF_BITS);
  float* lm = (float*)(ws + OFF_LM);

  prep_bits_kernel<<<NN / 4, 256, 0, stream>>>(labels, bits, lm, R, S, Cc);
  convert_kernel<<<(NN * 96) / 256, 256, 0, stream>>>(F, Ft);
  main_kernel<<<256, 512, 0, stream>>>(Ft, bits, R, S, Cc);
  finalize_kernel<<<1, 1024, 0, stream>>>(R, S, Cc, lm, out);
}